// Round 3
// baseline (8697.289 us; speedup 1.0000x reference)
//
#include <hip/hip_runtime.h>

typedef __bf16 bf16x8 __attribute__((ext_vector_type(8)));
typedef float f32x4 __attribute__((ext_vector_type(4)));
typedef unsigned long long u64x2 __attribute__((ext_vector_type(2)));

__device__ __forceinline__ unsigned short f2bf(float f) {
  unsigned u = __builtin_bit_cast(unsigned, f);
  u += 0x7fffu + ((u >> 16) & 1u);
  return (unsigned short)(u >> 16);
}
__device__ __forceinline__ float bf2f(unsigned short h) {
  unsigned u = ((unsigned)h) << 16;
  return __builtin_bit_cast(float, u);
}
__device__ __forceinline__ float sigmoidf_(float x) {
  return 1.f / (1.f + __expf(-x));
}
__device__ __forceinline__ float tanhf_(float x) {
  return 1.f - 2.f / (__expf(2.f * x) + 1.f);
}
// async global->LDS, 16B per lane. LDS dest must be wave-uniform base + lane*16.
__device__ __forceinline__ void gload16(const unsigned short* g, unsigned short* l) {
  __builtin_amdgcn_global_load_lds((const __attribute__((address_space(1))) void*)g,
                                   (__attribute__((address_space(3))) void*)l, 16, 0, 0);
}
// 16B load via two 8B device-scope relaxed atomic loads: bypasses (non-coherent) L1/L2,
// reads the LLC -- used for cross-block h exchange without any cache invalidate.
__device__ __forceinline__ bf16x8 aload16(const unsigned short* p) {
  const unsigned long long* q = (const unsigned long long*)p;
  u64x2 t;
  t.x = __hip_atomic_load(q, __ATOMIC_RELAXED, __HIP_MEMORY_SCOPE_AGENT);
  t.y = __hip_atomic_load(q + 1, __ATOMIC_RELAXED, __HIP_MEMORY_SCOPE_AGENT);
  return __builtin_bit_cast(bf16x8, t);
}

// ---------- weight cast kernels ----------

__global__ __launch_bounds__(256) void k_castf(const float* __restrict__ src,
                                               unsigned short* __restrict__ dst, int n4) {
  int i = blockIdx.x * 256 + threadIdx.x;
  if (i < n4) {
    float4 v = ((const float4*)src)[i];
    ushort4 o;
    o.x = f2bf(v.x); o.y = f2bf(v.y); o.z = f2bf(v.z); o.w = f2bf(v.w);
    ((ushort4*)dst)[i] = o;
  }
}

// transpose-cast: src fp32 (K,N) row-major -> dst bf16 (Npad,K) row-major, zero-pad n>=N
__global__ void k_cast_t(const float* __restrict__ src, unsigned short* __restrict__ dst,
                         int K, int N) {
  __shared__ float tile[32][33];
  int nx = blockIdx.x * 32, ky = blockIdx.y * 32;
  int tx = threadIdx.x, ty = threadIdx.y; // 32 x 8
  #pragma unroll
  for (int j = 0; j < 32; j += 8) {
    int n = nx + tx, k = ky + ty + j;
    tile[ty + j][tx] = (n < N) ? src[(long)k * N + n] : 0.f;
  }
  __syncthreads();
  #pragma unroll
  for (int j = 0; j < 32; j += 8) {
    int n = nx + ty + j, k = ky + tx;
    dst[(long)n * K + k] = f2bf(tile[tx][ty + j]);
  }
}

// ---------- LayerNorm kernels ----------

// layer-0 LN with (B,T,F)->(T,B,F) transpose, F=128, fp32 in -> bf16 out
__global__ __launch_bounds__(128) void k_ln0(const float* __restrict__ x,
                                             unsigned short* __restrict__ out,
                                             const float* __restrict__ g,
                                             const float* __restrict__ be) {
  int row = blockIdx.x;            // t*16 + b
  int t = row >> 4, b = row & 15;
  const float* src = x + ((long)b * 1024 + t) * 128;
  int i = threadIdx.x;
  float v = src[i];
  float s = v, q = v * v;
  #pragma unroll
  for (int off = 32; off > 0; off >>= 1) {
    s += __shfl_down(s, off);
    q += __shfl_down(q, off);
  }
  __shared__ float red[4];
  int wv = i >> 6;
  if ((i & 63) == 0) { red[wv] = s; red[2 + wv] = q; }
  __syncthreads();
  float S = red[0] + red[1], Q = red[2] + red[3];
  float mean = S * (1.f / 128.f);
  float var = Q * (1.f / 128.f) - mean * mean;
  float rs = rsqrtf(var + 1e-5f);
  out[(long)row * 128 + i] = f2bf((v - mean) * rs * g[i] + be[i]);
}

// generic LN over C=1024 fp32 rows -> bf16 out16; avg=1 averages time-pairs
__global__ __launch_bounds__(256) void k_ln(const float* __restrict__ in,
                                            unsigned short* __restrict__ out16,
                                            const float* __restrict__ g,
                                            const float* __restrict__ be, int avg) {
  int row = blockIdx.x;
  int tid = threadIdx.x;
  int col = tid * 4;
  float xv[4];
  if (avg) {
    int l = row >> 4, b = row & 15;
    const float* r0 = in + ((long)(2 * l) * 16 + b) * 1024;
    const float* r1 = r0 + 16 * 1024;
    float4 a = *(const float4*)(r0 + col);
    float4 bb = *(const float4*)(r1 + col);
    xv[0] = 0.5f * (a.x + bb.x);
    xv[1] = 0.5f * (a.y + bb.y);
    xv[2] = 0.5f * (a.z + bb.z);
    xv[3] = 0.5f * (a.w + bb.w);
  } else {
    float4 a = *(const float4*)(in + (long)row * 1024 + col);
    xv[0] = a.x; xv[1] = a.y; xv[2] = a.z; xv[3] = a.w;
  }
  float s = xv[0] + xv[1] + xv[2] + xv[3];
  float q = xv[0]*xv[0] + xv[1]*xv[1] + xv[2]*xv[2] + xv[3]*xv[3];
  #pragma unroll
  for (int off = 32; off > 0; off >>= 1) {
    s += __shfl_down(s, off);
    q += __shfl_down(q, off);
  }
  __shared__ float red[8];
  int wv = tid >> 6;
  if ((tid & 63) == 0) { red[wv] = s; red[4 + wv] = q; }
  __syncthreads();
  float S = red[0] + red[1] + red[2] + red[3];
  float Q = red[4] + red[5] + red[6] + red[7];
  float mean = S * (1.f / 1024.f);
  float var = Q * (1.f / 1024.f) - mean * mean;
  float rs = rsqrtf(var + 1e-5f);
  ushort4 o;
  o.x = f2bf((xv[0] - mean) * rs * g[col + 0] + be[col + 0]);
  o.y = f2bf((xv[1] - mean) * rs * g[col + 1] + be[col + 1]);
  o.z = f2bf((xv[2] - mean) * rs * g[col + 2] + be[col + 2]);
  o.w = f2bf((xv[3] - mean) * rs * g[col + 3] + be[col + 3]);
  *(ushort4*)(out16 + (long)row * 1024 + col) = o;
}

// ---------- GEMM: A (M,K) bf16 x Bt (N,K) bf16 ----------
// 128x128 tile, BK=64, 4 waves (2x2), each wave 64x64 = 4x4 fragments of 16x16x32.
// Staging via global_load_lds width=16 (m97 structure).
// MODE 0: fp32 out (M,N). MODE 1: + bias1[n]+bias2[n], fp32 out.
// MODE 2: fp32 scatter to (B=16, L=512, 1001) with n<1001 mask.
// Requires M%128==0, N%128==0, K%64==0.
template <int MODE>
__global__ __launch_bounds__(256) void k_gemm(const unsigned short* __restrict__ A,
                                              const unsigned short* __restrict__ Bt,
                                              void* __restrict__ Cout,
                                              const float* __restrict__ bias1,
                                              const float* __restrict__ bias2,
                                              int M, int N, int K) {
  __shared__ unsigned short As[128][64]; // linear (unpadded) -- required by global_load_lds
  __shared__ unsigned short Bs[128][64];
  const int bn = blockIdx.x * 128, bm = blockIdx.y * 128;
  const int tid = threadIdx.x;
  const int wave = tid >> 6, lane = tid & 63;
  const int wm = (wave >> 1) * 64, wn = (wave & 1) * 64;
  const int l15 = lane & 15, kq = lane >> 4;
  f32x4 acc[4][4] = {};
  const int r0 = tid >> 3;
  const int c0 = (tid & 7) * 8;
  const unsigned short* Ap = A + (long)(bm + r0) * K + c0;
  const unsigned short* Bp = Bt + (long)(bn + r0) * K + c0;
  for (int kb = 0; kb < K; kb += 64) {
    #pragma unroll
    for (int i = 0; i < 4; i++) {
      gload16(Ap + (long)(i * 32) * K + kb, &As[i * 32 + r0][c0]);
      gload16(Bp + (long)(i * 32) * K + kb, &Bs[i * 32 + r0][c0]);
    }
    __syncthreads();
    #pragma unroll
    for (int kk = 0; kk < 2; kk++) {
      const int kcol = kk * 32 + kq * 8;
      bf16x8 a[4], b[4];
      #pragma unroll
      for (int m = 0; m < 4; m++) a[m] = *(const bf16x8*)&As[wm + m * 16 + l15][kcol];
      #pragma unroll
      for (int n = 0; n < 4; n++) b[n] = *(const bf16x8*)&Bs[wn + n * 16 + l15][kcol];
      #pragma unroll
      for (int m = 0; m < 4; m++)
        #pragma unroll
        for (int n = 0; n < 4; n++)
          acc[m][n] = __builtin_amdgcn_mfma_f32_16x16x32_bf16(a[m], b[n], acc[m][n], 0, 0, 0);
    }
    __syncthreads();
  }
  #pragma unroll
  for (int m = 0; m < 4; m++)
    #pragma unroll
    for (int n = 0; n < 4; n++) {
      #pragma unroll
      for (int r = 0; r < 4; r++) {
        int gm = bm + wm + m * 16 + kq * 4 + r;
        int gn = bn + wn + n * 16 + l15;
        float v = acc[m][n][r];
        if (MODE == 0) {
          ((float*)Cout)[(long)gm * N + gn] = v;
        } else if (MODE == 1) {
          v += bias1[gn] + bias2[gn];
          ((float*)Cout)[(long)gm * N + gn] = v;
        } else {
          if (gn < 1001) {
            long oi = ((long)(gm & 15) * 512 + (gm >> 4)) * 1001 + gn;
            ((float*)Cout)[oi] = v;
          }
        }
      }
    }
}

// ---------- SRU scan (one time-chunk of Lc steps) ----------
__global__ __launch_bounds__(64) void k_scan(const float* __restrict__ U,
                                             const unsigned short* __restrict__ Res16,
                                             const float* __restrict__ vc,
                                             const float* __restrict__ bias,
                                             float* __restrict__ Hout,
                                             unsigned short* __restrict__ H16,
                                             float* __restrict__ cbuf,
                                             int Lc, int k4, int first) {
  int tid = blockIdx.x * 64 + threadIdx.x;
  int b = tid >> 10, hc = tid & 1023;
  float vf = vc[hc], vr = vc[1024 + hc];
  float bfv = bias[hc], brv = bias[1024 + hc];
  const int k = k4 ? 4 : 3;
  const long strideT = 16L * k * 1024;
  const long base0 = (long)b * k * 1024 + hc;
  const long rbase = (long)b * 1024 + hc;
  const long rstride = 16 * 1024;
  float c = first ? 0.f : cbuf[tid];
  for (int t0 = 0; t0 < Lc; t0 += 8) {
    float u0[8], u1[8], u2[8], rr[8];
    #pragma unroll
    for (int j = 0; j < 8; j++) {
      long o = base0 + (long)(t0 + j) * strideT;
      u0[j] = U[o];
      u1[j] = U[o + 1024];
      u2[j] = U[o + 2048];
      rr[j] = k4 ? U[o + 3072] : bf2f(Res16[rbase + (long)(t0 + j) * rstride]);
    }
    #pragma unroll
    for (int j = 0; j < 8; j++) {
      float f = sigmoidf_(u1[j] + vf * c + bfv);
      float r = sigmoidf_(u2[j] + vr * c + brv);
      c = f * c + (1.f - f) * u0[j];
      float h = r * c + (1.f - r) * rr[j];
      long oo = rbase + (long)(t0 + j) * rstride;
      Hout[oo] = h;
      if (H16) H16[oo] = f2bf(h);
    }
  }
  cbuf[tid] = c;
}

// ---------- persistent LSTM sequence kernel ----------
// 64 blocks x 1024 threads (16 waves), one block per CU (LDS ~149KB -> 1 block/CU;
// grid 64 <= 256 CUs, serial stream => all co-resident).
// Block j owns output channels [j*16, j*16+16) across 4 gates (64 gate-rows, LDS-resident).
// Cross-block h exchange: device-scope RELAXED atomics only (sc1 path, LLC-coherent) --
// NO release/acquire fences, so no per-step buffer_wbl2/buffer_inv; U stays warm in L2.
// Ordering: h-stores -> __syncthreads (per-wave vmcnt drain before s_barrier) -> flag store;
// poll exit -> (in-order issue) -> h atomic loads. Generations are monotonic across chunks.
__global__ __launch_bounds__(1024) void k_lstm_seq(
    const unsigned short* __restrict__ Whh,  // (4096,1024) bf16
    const float* __restrict__ U,             // (nT,16,4096) fp32 prep (bias added)
    unsigned short* __restrict__ hb0,        // (16,1024) bf16 ping
    unsigned short* __restrict__ hb1,        // (16,1024) bf16 pong
    float* __restrict__ cst,                 // (16,1024) fp32 cell (cross-launch)
    float* __restrict__ HsOut,               // (512,16,1024) fp32 base
    unsigned* __restrict__ flags,            // 64 barrier flags
    int nT, int tg0) {
  __shared__ unsigned short wlds[65536];     // 128 KB: frag-linear Whh slice
  __shared__ float P[4][16][66];             // k-group partials
  __shared__ float G[16][68];                // summed gates
  const int tid = threadIdx.x;
  const int j = blockIdx.x;
  const int c0 = j * 16;

  // ---- stage Whh slice, fragment-linear (writes lane-linear => conflict-free) ----
  // chunk m = ((g*32+ks)*64 + kq*16 + l)  holds Whh[g*1024+c0+l][ks*32+kq*8 .. +8)
  #pragma unroll
  for (int i = 0; i < 8; i++) {
    int m = tid + i * 1024;
    int g = m >> 11, ks = (m >> 6) & 31, kq2 = (m >> 4) & 3, l = m & 15;
    bf16x8 v = *(const bf16x8*)(Whh + (long)(g * 1024 + c0 + l) * 1024 + ks * 32 + kq2 * 8);
    *(bf16x8*)&wlds[m * 8] = v;
  }
  // cell state: tid<128 owns 2 channels (for packed 4B atomic h stores)
  float c_a = 0.f, c_b = 0.f;
  if (tid < 128) {
    float2 cc2 = *(const float2*)&cst[(long)(tid >> 3) * 1024 + c0 + 2 * (tid & 7)];
    c_a = cc2.x; c_b = cc2.y;
  }
  __syncthreads();

  const int wave = tid >> 6, lane = tid & 63;
  const int g = wave & 3, kgrp = wave >> 2;  // gate tile, k-group (256 wide)
  const int l15 = lane & 15, kq = lane >> 4;
  const unsigned short* wfrag = &wlds[((g * 32 + kgrp * 8) * 64 + lane) * 8];
  const int um = tid >> 6, ugc = tid & 63;   // G-phase mapping (batch, gate-col)
  const long upre_off = (long)(ugc >> 4) * 1024 + c0 + (ugc & 15);

  for (int t = 0; t < nT; t++) {
    const int tg = tg0 + t;
    const unsigned short* hin = (tg & 1) ? hb1 : hb0;
    unsigned short* hout = (tg & 1) ? hb0 : hb1;
    // U preload (normal cached load; L2 stays warm -- no invalidates in this kernel)
    float pre = U[((long)t * 16 + um) * 4096 + upre_off];
    // ---- MFMA partial over k in [kgrp*256, kgrp*256+256) ----
    f32x4 acc = {0.f, 0.f, 0.f, 0.f};
    const unsigned short* hp = hin + l15 * 1024 + kgrp * 256 + kq * 8;
    #pragma unroll
    for (int s = 0; s < 8; s++) {
      bf16x8 a = aload16(hp + s * 32);
      bf16x8 b = *(const bf16x8*)(wfrag + (long)s * 64 * 8);
      acc = __builtin_amdgcn_mfma_f32_16x16x32_bf16(a, b, acc, 0, 0, 0);
    }
    #pragma unroll
    for (int r = 0; r < 4; r++) P[kgrp][kq * 4 + r][g * 16 + l15] = acc[r];
    __syncthreads();
    G[um][ugc] = P[0][um][ugc] + P[1][um][ugc] + P[2][um][ugc] + P[3][um][ugc] + pre;
    __syncthreads();
    if (tid < 128) {
      int m = tid >> 3, p = tid & 7;
      int ca = 2 * p, cb = 2 * p + 1;
      float ig0 = G[m][ca],      fg0 = G[m][16 + ca];
      float gg0 = G[m][32 + ca], og0 = G[m][48 + ca];
      float ig1 = G[m][cb],      fg1 = G[m][16 + cb];
      float gg1 = G[m][32 + cb], og1 = G[m][48 + cb];
      float cn0 = sigmoidf_(fg0) * c_a + sigmoidf_(ig0) * tanhf_(gg0);
      float cn1 = sigmoidf_(fg1) * c_b + sigmoidf_(ig1) * tanhf_(gg1);
      float hn0 = sigmoidf_(og0) * tanhf_(cn0);
      float hn1 = sigmoidf_(og1) * tanhf_(cn1);
      c_a = cn0; c_b = cn1;
      unsigned pk = ((unsigned)f2bf(hn1) << 16) | (unsigned)f2bf(hn0);
      __hip_atomic_store((unsigned*)hout + m * 512 + (c0 >> 1) + p, pk,
                         __ATOMIC_RELAXED, __HIP_MEMORY_SCOPE_AGENT);
      float2 h2; h2.x = hn0; h2.y = hn1;
      *(float2*)&HsOut[((long)tg * 16 + m) * 1024 + c0 + ca] = h2;
    }
    // ---- device-scope grid barrier (all 64 blocks co-resident), fence-free ----
    __syncthreads();                 // per-wave vmcnt drain => h stores at LLC
    const unsigned gen = (unsigned)(tg + 1);
    if (tid == 0)
      __hip_atomic_store(&flags[j], gen, __ATOMIC_RELAXED, __HIP_MEMORY_SCOPE_AGENT);
    if (tid < 64) {
      unsigned v;
      do {
        __builtin_amdgcn_s_sleep(1);
        v = __hip_atomic_load(&flags[tid], __ATOMIC_RELAXED, __HIP_MEMORY_SCOPE_AGENT);
      } while (!__all(v >= gen));
    }
    __syncthreads();
  }
  if (tid < 128) {
    float2 cc2; cc2.x = c_a; cc2.y = c_b;
    *(float2*)&cst[(long)(tid >> 3) * 1024 + c0 + 2 * (tid & 7)] = cc2;
  }
}

// ---------- host ----------

extern "C" void kernel_launch(void* const* d_in, const int* in_sizes, int n_in,
                              void* d_out, int out_size, void* d_ws, size_t ws_size,
                              hipStream_t stream) {
  const float* x    = (const float*)d_in[0];
  const float* w0   = (const float*)d_in[1];
  const float* vc0  = (const float*)d_in[2];
  const float* b0   = (const float*)d_in[3];
  const float* g0   = (const float*)d_in[4];
  const float* be0  = (const float*)d_in[5];
  const float* Ws   = (const float*)d_in[6];
  const float* VCs  = (const float*)d_in[7];
  const float* Bsi  = (const float*)d_in[8];
  const float* Gs   = (const float*)d_in[9];
  const float* Bes  = (const float*)d_in[10];
  const float* Wih  = (const float*)d_in[11];
  const float* Whh  = (const float*)d_in[12];
  const float* bih  = (const float*)d_in[13];
  const float* bhh  = (const float*)d_in[14];
  const float* gh   = (const float*)d_in[15];
  const float* bh   = (const float*)d_in[16];
  const float* Wout = (const float*)d_in[17];

  char* ws = (char*)d_ws;
  size_t off = 0;
  auto alloc = [&](size_t bytes) {
    size_t r = off;
    off += (bytes + 255) & ~(size_t)255;
    return r;
  };
  unsigned short* W0t   = (unsigned short*)(ws + alloc(4096UL * 128 * 2));      //  1 MB
  unsigned short* Wst   = (unsigned short*)(ws + alloc(6UL * 3072 * 1024 * 2)); // 36 MB
  unsigned short* Wihb  = (unsigned short*)(ws + alloc(4096UL * 1024 * 2));     //  8 MB
  unsigned short* Whhb  = (unsigned short*)(ws + alloc(4096UL * 1024 * 2));     //  8 MB
  unsigned short* Woutt = (unsigned short*)(ws + alloc(1024UL * 1024 * 2));     //  2 MB
  unsigned short* Xn    = (unsigned short*)(ws + alloc(16384UL * 1024 * 2));    // 32 MB
  float*          Hbuf  = (float*)(ws + alloc(16384UL * 1024 * 4));             // 64 MB
  float*          Ubuf  = (float*)(ws + alloc(4096UL * 4096 * 4));              // 64 MB
  unsigned short* hb0   = (unsigned short*)(ws + alloc(16UL * 1024 * 2));
  unsigned short* hb1   = (unsigned short*)(ws + alloc(16UL * 1024 * 2));
  float*          cst   = (float*)(ws + alloc(16UL * 1024 * 4));
  float*          cscan = (float*)(ws + alloc(16UL * 1024 * 4));
  unsigned*       flags = (unsigned*)(ws + alloc(64UL * 4));
  // aliases (lifetimes do not overlap):
  float*          HsOut = Hbuf;              // (512,16,1024) fp32 during LSTM
  unsigned short* H16l6 = Xn + 8192L * 1024; // layer-6 h bf16 (8192 rows)
  unsigned short* LNout = Xn;                // final LN bf16 out (8192 rows)

  // ---- weight conversion ----
  k_cast_t<<<dim3(4096 / 32, 128 / 32), dim3(32, 8), 0, stream>>>(w0, W0t, 128, 4096);
  for (int i = 0; i < 6; i++)
    k_cast_t<<<dim3(3072 / 32, 1024 / 32), dim3(32, 8), 0, stream>>>(
        Ws + (long)i * 1024 * 3072, Wst + (long)i * 3072 * 1024, 1024, 3072);
  k_cast_t<<<dim3(1024 / 32, 1024 / 32), dim3(32, 8), 0, stream>>>(Wout, Woutt, 1024, 1001);
  k_castf<<<4096, 256, 0, stream>>>(Wih, Wihb, 4096 * 1024 / 4);
  k_castf<<<4096, 256, 0, stream>>>(Whh, Whhb, 4096 * 1024 / 4);
  // zero hb0, hb1, cst, cscan, flags (contiguous allocs)
  hipMemsetAsync(hb0, 0, 32768 + 32768 + 65536 + 65536 + 256, stream);

  const int CH_T = 256;           // timesteps per chunk
  const int CH_R = CH_T * 16;     // rows per chunk (4096)

  // ---- SRU layer 0 (k=4, K=128) ----
  k_ln0<<<16384, 128, 0, stream>>>(x, Xn, g0, be0);
  for (int c = 0; c < 4; c++) {
    k_gemm<0><<<dim3(4096 / 128, CH_R / 128), 256, 0, stream>>>(
        Xn + (long)c * CH_R * 128, W0t, Ubuf, nullptr, nullptr, CH_R, 4096, 128);
    k_scan<<<256, 64, 0, stream>>>(Ubuf, nullptr, vc0, b0,
                                   Hbuf + (long)c * CH_R * 1024, nullptr, cscan,
                                   CH_T, 1, c == 0);
  }

  // ---- SRU layers 1..6 (k=3, K=1024) ----
  for (int i = 0; i < 6; i++) {
    int L = (i < 3) ? 1024 : 512;
    int rows = L * 16;
    int avg = (i == 3) ? 1 : 0;
    k_ln<<<rows, 256, 0, stream>>>(Hbuf, Xn, Gs + i * 1024, Bes + i * 1024, avg);
    int nch = rows / CH_R;
    for (int c = 0; c < nch; c++) {
      k_gemm<0><<<dim3(3072 / 128, CH_R / 128), 256, 0, stream>>>(
          Xn + (long)c * CH_R * 1024, Wst + (long)i * 3072 * 1024, Ubuf, nullptr, nullptr,
          CH_R, 3072, 1024);
      k_scan<<<256, 64, 0, stream>>>(Ubuf, Xn + (long)c * CH_R * 1024,
                                     VCs + i * 2048, Bsi + i * 2048,
                                     Hbuf + (long)c * CH_R * 1024,
                                     (i == 5) ? (H16l6 + (long)c * CH_R * 1024) : nullptr,
                                     cscan, CH_T, 0, c == 0);
    }
  }

  // ---- LSTM: chunked input projection + persistent sequence kernel ----
  const int LCH_T = 128, LCH_R = LCH_T * 16; // 2048 rows per chunk
  for (int c = 0; c < 4; c++) {
    k_gemm<1><<<dim3(4096 / 128, LCH_R / 128), 256, 0, stream>>>(
        H16l6 + (long)c * LCH_R * 1024, Wihb, Ubuf, bih, bhh, LCH_R, 4096, 1024);
    k_lstm_seq<<<64, 1024, 0, stream>>>(Whhb, Ubuf, hb0, hb1, cst, HsOut, flags,
                                        LCH_T, c * LCH_T);
  }

  // ---- final LN + output projection ----
  k_ln<<<8192, 256, 0, stream>>>(HsOut, LNout, gh, bh, 0);
  k_gemm<2><<<dim3(1024 / 128, 8192 / 128), 256, 0, stream>>>(LNout, Woutt, d_out, nullptr,
                                                              nullptr, 8192, 1024, 1024);
}

// Round 4
// 6233.864 us; speedup vs baseline: 1.3952x; 1.3952x over previous
//
#include <hip/hip_runtime.h>

typedef __bf16 bf16x8 __attribute__((ext_vector_type(8)));
typedef float f32x4 __attribute__((ext_vector_type(4)));

__device__ __forceinline__ unsigned short f2bf(float f) {
  unsigned u = __builtin_bit_cast(unsigned, f);
  u += 0x7fffu + ((u >> 16) & 1u);
  return (unsigned short)(u >> 16);
}
__device__ __forceinline__ float bf2f(unsigned short h) {
  unsigned u = ((unsigned)h) << 16;
  return __builtin_bit_cast(float, u);
}
__device__ __forceinline__ float sigmoidf_(float x) {
  return 1.f / (1.f + __expf(-x));
}
__device__ __forceinline__ float tanhf_(float x) {
  return 1.f - 2.f / (__expf(2.f * x) + 1.f);
}
// async global->LDS, 16B per lane. LDS dest must be wave-uniform base + lane*16.
__device__ __forceinline__ void gload16(const unsigned short* g, unsigned short* l) {
  __builtin_amdgcn_global_load_lds((const __attribute__((address_space(1))) void*)g,
                                   (__attribute__((address_space(3))) void*)l, 16, 0, 0);
}

// ---------- weight cast kernels ----------

__global__ __launch_bounds__(256) void k_castf(const float* __restrict__ src,
                                               unsigned short* __restrict__ dst, int n4) {
  int i = blockIdx.x * 256 + threadIdx.x;
  if (i < n4) {
    float4 v = ((const float4*)src)[i];
    ushort4 o;
    o.x = f2bf(v.x); o.y = f2bf(v.y); o.z = f2bf(v.z); o.w = f2bf(v.w);
    ((ushort4*)dst)[i] = o;
  }
}

// transpose-cast: src fp32 (K,N) row-major -> dst bf16 (Npad,K) row-major, zero-pad n>=N
__global__ void k_cast_t(const float* __restrict__ src, unsigned short* __restrict__ dst,
                         int K, int N) {
  __shared__ float tile[32][33];
  int nx = blockIdx.x * 32, ky = blockIdx.y * 32;
  int tx = threadIdx.x, ty = threadIdx.y; // 32 x 8
  #pragma unroll
  for (int j = 0; j < 32; j += 8) {
    int n = nx + tx, k = ky + ty + j;
    tile[ty + j][tx] = (n < N) ? src[(long)k * N + n] : 0.f;
  }
  __syncthreads();
  #pragma unroll
  for (int j = 0; j < 32; j += 8) {
    int n = nx + ty + j, k = ky + tx;
    dst[(long)n * K + k] = f2bf(tile[tx][ty + j]);
  }
}

// ---------- LayerNorm kernels ----------

// layer-0 LN with (B,T,F)->(T,B,F) transpose, F=128, fp32 in -> bf16 out
__global__ __launch_bounds__(128) void k_ln0(const float* __restrict__ x,
                                             unsigned short* __restrict__ out,
                                             const float* __restrict__ g,
                                             const float* __restrict__ be) {
  int row = blockIdx.x;            // t*16 + b
  int t = row >> 4, b = row & 15;
  const float* src = x + ((long)b * 1024 + t) * 128;
  int i = threadIdx.x;
  float v = src[i];
  float s = v, q = v * v;
  #pragma unroll
  for (int off = 32; off > 0; off >>= 1) {
    s += __shfl_down(s, off);
    q += __shfl_down(q, off);
  }
  __shared__ float red[4];
  int wv = i >> 6;
  if ((i & 63) == 0) { red[wv] = s; red[2 + wv] = q; }
  __syncthreads();
  float S = red[0] + red[1], Q = red[2] + red[3];
  float mean = S * (1.f / 128.f);
  float var = Q * (1.f / 128.f) - mean * mean;
  float rs = rsqrtf(var + 1e-5f);
  out[(long)row * 128 + i] = f2bf((v - mean) * rs * g[i] + be[i]);
}

// generic LN over C=1024 fp32 rows -> bf16 out16; avg=1 averages time-pairs
__global__ __launch_bounds__(256) void k_ln(const float* __restrict__ in,
                                            unsigned short* __restrict__ out16,
                                            const float* __restrict__ g,
                                            const float* __restrict__ be, int avg) {
  int row = blockIdx.x;
  int tid = threadIdx.x;
  int col = tid * 4;
  float xv[4];
  if (avg) {
    int l = row >> 4, b = row & 15;
    const float* r0 = in + ((long)(2 * l) * 16 + b) * 1024;
    const float* r1 = r0 + 16 * 1024;
    float4 a = *(const float4*)(r0 + col);
    float4 bb = *(const float4*)(r1 + col);
    xv[0] = 0.5f * (a.x + bb.x);
    xv[1] = 0.5f * (a.y + bb.y);
    xv[2] = 0.5f * (a.z + bb.z);
    xv[3] = 0.5f * (a.w + bb.w);
  } else {
    float4 a = *(const float4*)(in + (long)row * 1024 + col);
    xv[0] = a.x; xv[1] = a.y; xv[2] = a.z; xv[3] = a.w;
  }
  float s = xv[0] + xv[1] + xv[2] + xv[3];
  float q = xv[0]*xv[0] + xv[1]*xv[1] + xv[2]*xv[2] + xv[3]*xv[3];
  #pragma unroll
  for (int off = 32; off > 0; off >>= 1) {
    s += __shfl_down(s, off);
    q += __shfl_down(q, off);
  }
  __shared__ float red[8];
  int wv = tid >> 6;
  if ((tid & 63) == 0) { red[wv] = s; red[4 + wv] = q; }
  __syncthreads();
  float S = red[0] + red[1] + red[2] + red[3];
  float Q = red[4] + red[5] + red[6] + red[7];
  float mean = S * (1.f / 1024.f);
  float var = Q * (1.f / 1024.f) - mean * mean;
  float rs = rsqrtf(var + 1e-5f);
  ushort4 o;
  o.x = f2bf((xv[0] - mean) * rs * g[col + 0] + be[col + 0]);
  o.y = f2bf((xv[1] - mean) * rs * g[col + 1] + be[col + 1]);
  o.z = f2bf((xv[2] - mean) * rs * g[col + 2] + be[col + 2]);
  o.w = f2bf((xv[3] - mean) * rs * g[col + 3] + be[col + 3]);
  *(ushort4*)(out16 + (long)row * 1024 + col) = o;
}

// ---------- GEMM: A (M,K) bf16 x Bt (N,K) bf16 ----------
// 128x128 tile, BK=64, 4 waves (2x2), each wave 64x64 = 4x4 fragments of 16x16x32.
// Staging via global_load_lds width=16 (m97 structure).
// MODE 0: fp32 out (M,N). MODE 1: + bias1[n]+bias2[n], fp32 out.
// MODE 2: fp32 scatter to (B=16, L=512, 1001) with n<1001 mask.
// Requires M%128==0, N%128==0, K%64==0.
template <int MODE>
__global__ __launch_bounds__(256) void k_gemm(const unsigned short* __restrict__ A,
                                              const unsigned short* __restrict__ Bt,
                                              void* __restrict__ Cout,
                                              const float* __restrict__ bias1,
                                              const float* __restrict__ bias2,
                                              int M, int N, int K) {
  __shared__ unsigned short As[128][64]; // linear (unpadded) -- required by global_load_lds
  __shared__ unsigned short Bs[128][64];
  const int bn = blockIdx.x * 128, bm = blockIdx.y * 128;
  const int tid = threadIdx.x;
  const int wave = tid >> 6, lane = tid & 63;
  const int wm = (wave >> 1) * 64, wn = (wave & 1) * 64;
  const int l15 = lane & 15, kq = lane >> 4;
  f32x4 acc[4][4] = {};
  const int r0 = tid >> 3;
  const int c0 = (tid & 7) * 8;
  const unsigned short* Ap = A + (long)(bm + r0) * K + c0;
  const unsigned short* Bp = Bt + (long)(bn + r0) * K + c0;
  for (int kb = 0; kb < K; kb += 64) {
    #pragma unroll
    for (int i = 0; i < 4; i++) {
      gload16(Ap + (long)(i * 32) * K + kb, &As[i * 32 + r0][c0]);
      gload16(Bp + (long)(i * 32) * K + kb, &Bs[i * 32 + r0][c0]);
    }
    __syncthreads();
    #pragma unroll
    for (int kk = 0; kk < 2; kk++) {
      const int kcol = kk * 32 + kq * 8;
      bf16x8 a[4], b[4];
      #pragma unroll
      for (int m = 0; m < 4; m++) a[m] = *(const bf16x8*)&As[wm + m * 16 + l15][kcol];
      #pragma unroll
      for (int n = 0; n < 4; n++) b[n] = *(const bf16x8*)&Bs[wn + n * 16 + l15][kcol];
      #pragma unroll
      for (int m = 0; m < 4; m++)
        #pragma unroll
        for (int n = 0; n < 4; n++)
          acc[m][n] = __builtin_amdgcn_mfma_f32_16x16x32_bf16(a[m], b[n], acc[m][n], 0, 0, 0);
    }
    __syncthreads();
  }
  #pragma unroll
  for (int m = 0; m < 4; m++)
    #pragma unroll
    for (int n = 0; n < 4; n++) {
      #pragma unroll
      for (int r = 0; r < 4; r++) {
        int gm = bm + wm + m * 16 + kq * 4 + r;
        int gn = bn + wn + n * 16 + l15;
        float v = acc[m][n][r];
        if (MODE == 0) {
          ((float*)Cout)[(long)gm * N + gn] = v;
        } else if (MODE == 1) {
          v += bias1[gn] + bias2[gn];
          ((float*)Cout)[(long)gm * N + gn] = v;
        } else {
          if (gn < 1001) {
            long oi = ((long)(gm & 15) * 512 + (gm >> 4)) * 1001 + gn;
            ((float*)Cout)[oi] = v;
          }
        }
      }
    }
}

// ---------- SRU scan (one time-chunk of Lc steps) ----------
// 16384 threads, one per (b,hc). U fp32 chunk (Lc*16 rows, k*1024).
// Res16 bf16 residual rows (nullptr if k4: residual is U col 3).
// 16-deep time-batch: ~16KB in flight per wave (1 wave/CU -> latency-bound; MLP is the lever).
// Hout nullable (layer 6 fp32 h is never consumed).
__global__ __launch_bounds__(64) void k_scan(const float* __restrict__ U,
                                             const unsigned short* __restrict__ Res16,
                                             const float* __restrict__ vc,
                                             const float* __restrict__ bias,
                                             float* __restrict__ Hout,
                                             unsigned short* __restrict__ H16,
                                             float* __restrict__ cbuf,
                                             int Lc, int k4, int first) {
  int tid = blockIdx.x * 64 + threadIdx.x;
  int b = tid >> 10, hc = tid & 1023;
  float vf = vc[hc], vr = vc[1024 + hc];
  float bfv = bias[hc], brv = bias[1024 + hc];
  const int k = k4 ? 4 : 3;
  const long strideT = 16L * k * 1024;
  const long base0 = (long)b * k * 1024 + hc;
  const long rbase = (long)b * 1024 + hc;
  const long rstride = 16 * 1024;
  float c = first ? 0.f : cbuf[tid];
  for (int t0 = 0; t0 < Lc; t0 += 16) {
    float u0[16], u1[16], u2[16], rr[16];
    #pragma unroll
    for (int j = 0; j < 16; j++) {
      long o = base0 + (long)(t0 + j) * strideT;
      u0[j] = U[o];
      u1[j] = U[o + 1024];
      u2[j] = U[o + 2048];
      rr[j] = k4 ? U[o + 3072] : bf2f(Res16[rbase + (long)(t0 + j) * rstride]);
    }
    #pragma unroll
    for (int j = 0; j < 16; j++) {
      float f = sigmoidf_(u1[j] + vf * c + bfv);
      float r = sigmoidf_(u2[j] + vr * c + brv);
      c = f * c + (1.f - f) * u0[j];
      float h = r * c + (1.f - r) * rr[j];
      long oo = rbase + (long)(t0 + j) * rstride;
      if (Hout) Hout[oo] = h;
      if (H16) H16[oo] = f2bf(h);
    }
  }
  cbuf[tid] = c;
}

// ---------- LSTM single step ----------
// 256 blocks x 256 threads (4 waves). Block j owns channels c0=j*4, all 4 gates,
// all 16 batches. K=1024 split across 4 waves, LDS reduce, then cell update.
// Prep / HsOutp are pre-offset to this timestep.
__global__ __launch_bounds__(256) void k_lstm_step(
    const unsigned short* __restrict__ Whhb, // (4096,1024) bf16
    const float* __restrict__ Prep,          // (16,4096) fp32 for this t
    const unsigned short* __restrict__ hin,  // (16,1024) bf16
    unsigned short* __restrict__ hout,       // (16,1024) bf16
    float* __restrict__ cst,                 // (16,1024) fp32
    float* __restrict__ HsOutp) {            // (16,1024) fp32 for this t
  const int tid = threadIdx.x;
  const int wave = tid >> 6, lane = tid & 63;
  const int j = blockIdx.x;
  const int c0 = j * 4;
  const int l15 = lane & 15, kq = lane >> 4;
  const int wrow = (l15 >> 2) * 1024 + c0 + (l15 & 3);
  f32x4 acc = {0.f, 0.f, 0.f, 0.f};
  const unsigned short* hp = hin + l15 * 1024 + wave * 256 + kq * 8;
  const unsigned short* wp = Whhb + (long)wrow * 1024 + wave * 256 + kq * 8;
  #pragma unroll
  for (int kb = 0; kb < 256; kb += 32) {
    bf16x8 a = *(const bf16x8*)(hp + kb);
    bf16x8 w = *(const bf16x8*)(wp + kb);
    acc = __builtin_amdgcn_mfma_f32_16x16x32_bf16(a, w, acc, 0, 0, 0);
  }
  __shared__ float P[4][16][16];
  __shared__ float G[16][16];
  #pragma unroll
  for (int r = 0; r < 4; r++) {
    int m = kq * 4 + r; // batch
    P[wave][m][l15] = acc[r];
  }
  __syncthreads();
  {
    int m = tid >> 4, col = tid & 15;
    int gate = col >> 2, ch = c0 + (col & 3);
    float pre = Prep[(long)m * 4096 + gate * 1024 + ch];
    G[m][col] = P[0][m][col] + P[1][m][col] + P[2][m][col] + P[3][m][col] + pre;
  }
  __syncthreads();
  if (tid < 64) {
    int m = tid & 15, chl = tid >> 4;
    float ig = G[m][0 * 4 + chl];
    float fg = G[m][1 * 4 + chl];
    float gg = G[m][2 * 4 + chl];
    float og = G[m][3 * 4 + chl];
    long ci = (long)m * 1024 + c0 + chl;
    float cold = cst[ci];
    float cn = sigmoidf_(fg) * cold + sigmoidf_(ig) * tanhf_(gg);
    float hn = sigmoidf_(og) * tanhf_(cn);
    cst[ci] = cn;
    hout[ci] = f2bf(hn);
    HsOutp[(long)m * 1024 + c0 + chl] = hn;
  }
}

// ---------- host ----------

extern "C" void kernel_launch(void* const* d_in, const int* in_sizes, int n_in,
                              void* d_out, int out_size, void* d_ws, size_t ws_size,
                              hipStream_t stream) {
  const float* x    = (const float*)d_in[0];
  const float* w0   = (const float*)d_in[1];
  const float* vc0  = (const float*)d_in[2];
  const float* b0   = (const float*)d_in[3];
  const float* g0   = (const float*)d_in[4];
  const float* be0  = (const float*)d_in[5];
  const float* Ws   = (const float*)d_in[6];
  const float* VCs  = (const float*)d_in[7];
  const float* Bsi  = (const float*)d_in[8];
  const float* Gs   = (const float*)d_in[9];
  const float* Bes  = (const float*)d_in[10];
  const float* Wih  = (const float*)d_in[11];
  const float* Whh  = (const float*)d_in[12];
  const float* bih  = (const float*)d_in[13];
  const float* bhh  = (const float*)d_in[14];
  const float* gh   = (const float*)d_in[15];
  const float* bh   = (const float*)d_in[16];
  const float* Wout = (const float*)d_in[17];

  char* ws = (char*)d_ws;
  size_t off = 0;
  auto alloc = [&](size_t bytes) {
    size_t r = off;
    off += (bytes + 255) & ~(size_t)255;
    return r;
  };
  unsigned short* W0t   = (unsigned short*)(ws + alloc(4096UL * 128 * 2));      //  1 MB
  unsigned short* Wst   = (unsigned short*)(ws + alloc(6UL * 3072 * 1024 * 2)); // 36 MB
  unsigned short* Wihb  = (unsigned short*)(ws + alloc(4096UL * 1024 * 2));     //  8 MB
  unsigned short* Whhb  = (unsigned short*)(ws + alloc(4096UL * 1024 * 2));     //  8 MB
  unsigned short* Woutt = (unsigned short*)(ws + alloc(1024UL * 1024 * 2));     //  2 MB
  unsigned short* Xn    = (unsigned short*)(ws + alloc(16384UL * 1024 * 2));    // 32 MB
  float*          Hbuf  = (float*)(ws + alloc(16384UL * 1024 * 4));             // 64 MB
  float*          Ubuf  = (float*)(ws + alloc(4096UL * 4096 * 4));              // 64 MB
  unsigned short* hb0   = (unsigned short*)(ws + alloc(16UL * 1024 * 2));
  unsigned short* hb1   = (unsigned short*)(ws + alloc(16UL * 1024 * 2));
  float*          cst   = (float*)(ws + alloc(16UL * 1024 * 4));
  float*          cscan = (float*)(ws + alloc(16UL * 1024 * 4));
  // aliases (lifetimes do not overlap):
  float*          HsOut = Hbuf;              // (512,16,1024) fp32 during LSTM
  unsigned short* H16l6 = Xn + 8192L * 1024; // layer-6 h bf16 (8192 rows)
  unsigned short* LNout = Xn;                // final LN bf16 out (8192 rows)

  // ---- weight conversion ----
  k_cast_t<<<dim3(4096 / 32, 128 / 32), dim3(32, 8), 0, stream>>>(w0, W0t, 128, 4096);
  for (int i = 0; i < 6; i++)
    k_cast_t<<<dim3(3072 / 32, 1024 / 32), dim3(32, 8), 0, stream>>>(
        Ws + (long)i * 1024 * 3072, Wst + (long)i * 3072 * 1024, 1024, 3072);
  k_cast_t<<<dim3(1024 / 32, 1024 / 32), dim3(32, 8), 0, stream>>>(Wout, Woutt, 1024, 1001);
  k_castf<<<4096, 256, 0, stream>>>(Wih, Wihb, 4096 * 1024 / 4);
  k_castf<<<4096, 256, 0, stream>>>(Whh, Whhb, 4096 * 1024 / 4);
  hipMemsetAsync(hb0, 0, 32768 + 32768 + 65536, stream); // hb0, hb1, cst contiguous

  const int CH_T = 256;           // timesteps per chunk
  const int CH_R = CH_T * 16;     // rows per chunk (4096)

  // ---- SRU layer 0 (k=4, K=128) ----
  k_ln0<<<16384, 128, 0, stream>>>(x, Xn, g0, be0);
  for (int c = 0; c < 4; c++) {
    k_gemm<0><<<dim3(4096 / 128, CH_R / 128), 256, 0, stream>>>(
        Xn + (long)c * CH_R * 128, W0t, Ubuf, nullptr, nullptr, CH_R, 4096, 128);
    k_scan<<<256, 64, 0, stream>>>(Ubuf, nullptr, vc0, b0,
                                   Hbuf + (long)c * CH_R * 1024, nullptr, cscan,
                                   CH_T, 1, c == 0);
  }

  // ---- SRU layers 1..6 (k=3, K=1024) ----
  for (int i = 0; i < 6; i++) {
    int L = (i < 3) ? 1024 : 512;
    int rows = L * 16;
    int avg = (i == 3) ? 1 : 0;
    k_ln<<<rows, 256, 0, stream>>>(Hbuf, Xn, Gs + i * 1024, Bes + i * 1024, avg);
    int nch = rows / CH_R;
    for (int c = 0; c < nch; c++) {
      k_gemm<0><<<dim3(3072 / 128, CH_R / 128), 256, 0, stream>>>(
          Xn + (long)c * CH_R * 1024, Wst + (long)i * 3072 * 1024, Ubuf, nullptr, nullptr,
          CH_R, 3072, 1024);
      k_scan<<<256, 64, 0, stream>>>(Ubuf, Xn + (long)c * CH_R * 1024,
                                     VCs + i * 2048, Bsi + i * 2048,
                                     (i == 5) ? nullptr : (Hbuf + (long)c * CH_R * 1024),
                                     (i == 5) ? (H16l6 + (long)c * CH_R * 1024) : nullptr,
                                     cscan, CH_T, 0, c == 0);
    }
  }

  // ---- LSTM: chunked input projection + 512 step kernels ----
  // (HsOut aliases Hbuf: layer-6 fp32 h is no longer needed)
  const int LCH_T = 256, LCH_R = LCH_T * 16; // 4096 rows per chunk (fills Ubuf exactly)
  for (int c = 0; c < 2; c++) {
    k_gemm<1><<<dim3(4096 / 128, LCH_R / 128), 256, 0, stream>>>(
        H16l6 + (long)c * LCH_R * 1024, Wihb, Ubuf, bih, bhh, LCH_R, 4096, 1024);
    for (int tl = 0; tl < LCH_T; tl++) {
      int tg = c * LCH_T + tl;
      unsigned short* hin = (tg & 1) ? hb1 : hb0;
      unsigned short* hout = (tg & 1) ? hb0 : hb1;
      k_lstm_step<<<256, 256, 0, stream>>>(Whhb, Ubuf + (long)tl * 16 * 4096, hin, hout,
                                           cst, HsOut + (long)tg * 16 * 1024);
    }
  }

  // ---- final LN + output projection ----
  k_ln<<<8192, 256, 0, stream>>>(HsOut, LNout, gh, bh, 0);
  k_gemm<2><<<dim3(1024 / 128, 8192 / 128), 256, 0, stream>>>(LNout, Woutt, d_out, nullptr,
                                                              nullptr, 8192, 1024, 1024);
}